// Round 1
// baseline (615.443 us; speedup 1.0000x reference)
//
#include <hip/hip_runtime.h>
#include <hip/hip_bf16.h>

#define NT 8
#define MEMC 512
#define HID 256
#define C 128   // IN_C == OUT_C

typedef __attribute__((ext_vector_type(8))) short short8;
typedef __attribute__((ext_vector_type(4))) short short4v;
typedef __attribute__((ext_vector_type(4))) float f32x4;

__device__ inline short f2bf(float f) {
    union { __hip_bfloat16 b; short s; } u;
    u.b = __float2bfloat16(f);
    return u.s;
}

// ---------------------------------------------------------------------------
// K1: idx init (-1), hist+cursor zero, generator hidden layers h_wg/h_bg
//     [8][256].  Generator blocks: 4-way wave K-split + LDS reduce.
// ---------------------------------------------------------------------------
__global__ __launch_bounds__(256) void k1_init_genh(
    const float* __restrict__ edge_feas,
    const float* __restrict__ wg_w1, const float* __restrict__ wg_b1,
    const float* __restrict__ wg_w2, const float* __restrict__ wg_b2,
    const float* __restrict__ bg_w1, const float* __restrict__ bg_b1,
    const float* __restrict__ bg_w2, const float* __restrict__ bg_b2,
    int* __restrict__ hist, int* __restrict__ cursor,
    int* __restrict__ idx, int idx_cap,
    float* __restrict__ h_wg, float* __restrict__ h_bg,
    int n_init_blocks)
{
    int b = blockIdx.x, tid = threadIdx.x;
    if (b < n_init_blocks) {
        int pos = b * 1024 + tid * 4;
        if (pos < idx_cap) *(int4*)(idx + pos) = make_int4(-1, -1, -1, -1);
        return;
    }
    if (b == n_init_blocks) {
        if (tid < NT) { hist[tid] = 0; cursor[tid * 16] = 0; }
        return;
    }
    int gb = b - n_init_blocks - 1;          // 0..15
    int t = gb & 7;
    int gen = gb >> 3;
    const float* w1 = gen ? bg_w1 : wg_w1;
    const float* b1 = gen ? bg_b1 : wg_b1;
    const float* w2 = gen ? bg_w2 : wg_w2;
    const float* b2 = gen ? bg_b2 : wg_b2;
    float* hout = gen ? h_bg : h_wg;

    __shared__ float m[MEMC];
    __shared__ float part[4][HID];
    __shared__ float h1[HID];
    m[tid]       = edge_feas[t * MEMC + tid];
    m[tid + 256] = edge_feas[t * MEMC + tid + 256];
    __syncthreads();

    int w = tid >> 6, l = tid & 63;
    // layer 1: K=512, wave w owns k in [w*128, w*128+128)
    {
        float ax = 0.f, ay = 0.f, az = 0.f, aw = 0.f;
        const float* wp = w1 + (size_t)(w * 128) * HID + 4 * l;
        #pragma unroll 8
        for (int k = 0; k < 128; ++k) {
            float4 v = *(const float4*)(wp + (size_t)k * HID);
            float mk = m[w * 128 + k];
            ax += mk * v.x; ay += mk * v.y; az += mk * v.z; aw += mk * v.w;
        }
        *(float4*)&part[w][4 * l] = make_float4(ax, ay, az, aw);
    }
    __syncthreads();
    {
        float s = part[0][tid] + part[1][tid] + part[2][tid] + part[3][tid] + b1[tid];
        h1[tid] = fmaxf(s, 0.f);
    }
    __syncthreads();
    // layer 2: K=256, wave w owns k in [w*64, w*64+64)
    {
        float ax = 0.f, ay = 0.f, az = 0.f, aw = 0.f;
        const float* wp = w2 + (size_t)(w * 64) * HID + 4 * l;
        #pragma unroll 8
        for (int k = 0; k < 64; ++k) {
            float4 v = *(const float4*)(wp + (size_t)k * HID);
            float hk = h1[w * 64 + k];
            ax += hk * v.x; ay += hk * v.y; az += hk * v.z; aw += hk * v.w;
        }
        *(float4*)&part[w][4 * l] = make_float4(ax, ay, az, aw);
    }
    __syncthreads();
    {
        float s = part[0][tid] + part[1][tid] + part[2][tid] + part[3][tid] + b2[tid];
        hout[t * HID + tid] = fmaxf(s, 0.f);
    }
}

// ---------------------------------------------------------------------------
// K2: type histogram + third layers.
//   W blocks (256): 64 cols each, 4-way K-split, 8 types per load.
//   Bias block (1): 128 cols, 2-way K-split, 8 types per load.
// ---------------------------------------------------------------------------
__global__ __launch_bounds__(256) void k2_hist_genw(
    const int* __restrict__ type_vec, int N,
    const float* __restrict__ h_wg, const float* __restrict__ h_bg,
    const float* __restrict__ wg_w3, const float* __restrict__ wg_b3,
    const float* __restrict__ bg_w3, const float* __restrict__ bg_b3,
    int* __restrict__ hist, short* __restrict__ Wkn, float* __restrict__ Bias,
    int n_hist_blocks)
{
    int b = blockIdx.x, tid = threadIdx.x;
    __shared__ float sh[2048];
    __shared__ float sp[2048];
    if (b < n_hist_blocks) {
        __shared__ int lh[NT];
        if (tid < NT) lh[tid] = 0;
        __syncthreads();
        int base = b * 1024 + tid;
        #pragma unroll
        for (int i = 0; i < 4; ++i) {
            int n = base + i * 256;
            if (n < N) atomicAdd(&lh[type_vec[n]], 1);
        }
        __syncthreads();
        if (tid < NT) atomicAdd(&hist[tid], lh[tid]);
        return;
    }
    int gb = b - n_hist_blocks;
    if (gb < 256) {
        for (int i = tid; i < 2048; i += 256) sh[i] = h_wg[i];
        __syncthreads();
        int cl = tid & 63, p = tid >> 6;
        int col = gb * 64 + cl;
        float acc[NT];
        #pragma unroll
        for (int t = 0; t < NT; ++t) acc[t] = 0.f;
        const float* wp = wg_w3 + (size_t)(p * 64) * (C * C) + col;
        #pragma unroll 8
        for (int j = 0; j < 64; ++j) {
            float v = wp[(size_t)j * (C * C)];
            #pragma unroll
            for (int t = 0; t < NT; ++t) acc[t] += sh[t * 256 + p * 64 + j] * v;
        }
        #pragma unroll
        for (int t = 0; t < NT; ++t) sp[p * 512 + t * 64 + cl] = acc[t];
        __syncthreads();
        #pragma unroll
        for (int r = 0; r < 2; ++r) {
            int o = tid + 256 * r;               // 0..511
            int t = o >> 6, c2 = o & 63;
            float s = sp[t * 64 + c2] + sp[512 + t * 64 + c2]
                    + sp[1024 + t * 64 + c2] + sp[1536 + t * 64 + c2]
                    + wg_b3[gb * 64 + c2];
            Wkn[t * (C * C) + gb * 64 + c2] = f2bf(s);
        }
        return;
    }
    // bias block
    for (int i = tid; i < 2048; i += 256) sh[i] = h_bg[i];
    __syncthreads();
    int cl = tid & 127, p = tid >> 7;
    float acc[NT];
    #pragma unroll
    for (int t = 0; t < NT; ++t) acc[t] = 0.f;
    const float* wp = bg_w3 + (size_t)(p * 128) * C + cl;
    #pragma unroll 8
    for (int j = 0; j < 128; ++j) {
        float v = wp[(size_t)j * C];
        #pragma unroll
        for (int t = 0; t < NT; ++t) acc[t] += sh[t * 256 + p * 128 + j] * v;
    }
    #pragma unroll
    for (int t = 0; t < NT; ++t) sp[p * 1024 + t * 128 + cl] = acc[t];
    __syncthreads();
    #pragma unroll
    for (int r = 0; r < 4; ++r) {
        int o = tid + 256 * r;                   // 0..1023
        int t = o >> 7, c2 = o & 127;
        Bias[t * C + c2] = sp[t * 128 + c2] + sp[1024 + t * 128 + c2] + bg_b3[c2];
    }
}

// ---------------------------------------------------------------------------
// K4: ballot scatter into type-sorted idx[] (seg computed inline from hist)
//     + W transpose Wkn[t][k][n] -> Wt[t][n][k]
// ---------------------------------------------------------------------------
__global__ __launch_bounds__(256) void k4_scatter_transpose(
    const int* __restrict__ type_vec, int N,
    const int* __restrict__ hist, int* __restrict__ cursor,
    int* __restrict__ idx,
    const short* __restrict__ Wkn, short* __restrict__ Wt,
    int n_scatter_blocks)
{
    int b = blockIdx.x, tid = threadIdx.x;
    if (b >= n_scatter_blocks) {
        int t = b - n_scatter_blocks;            // 0..7
        __shared__ short tile[C][C + 8];
        const short* src = Wkn + t * (C * C);
        for (int i = tid; i < C * C; i += 256)
            tile[i >> 7][i & 127] = src[i];
        __syncthreads();
        short* dst = Wt + t * (C * C);
        for (int i = tid; i < C * C; i += 256)
            dst[i] = tile[i & 127][i >> 7];
        return;
    }
    int seg[NT];
    {
        int s = 0;
        #pragma unroll
        for (int t = 0; t < NT; ++t) { seg[t] = s; s += ((hist[t] + 63) >> 6) << 6; }
    }
    int lane = tid & 63;
    int wave = b * 4 + (tid >> 6);
    int start = wave * 1024;
    if (start >= N) return;

    int cnt[NT];
    #pragma unroll
    for (int t = 0; t < NT; ++t) cnt[t] = 0;
    for (int c = 0; c < 16; ++c) {
        int n = start + c * 64 + lane;
        int mt = (n < N) ? type_vec[n] : NT;
        #pragma unroll
        for (int t = 0; t < NT; ++t)
            cnt[t] += __popcll(__ballot(mt == t));
    }
    int base = 0;
    if (lane < NT) base = atomicAdd(&cursor[lane * 16], cnt[lane]);
    int run[NT];
    #pragma unroll
    for (int t = 0; t < NT; ++t) run[t] = seg[t] + __shfl(base, t, 64);
    unsigned long long below = (1ULL << lane) - 1ULL;
    for (int c = 0; c < 16; ++c) {
        int n = start + c * 64 + lane;
        int mt = (n < N) ? type_vec[n] : NT;
        int mypos = 0;
        #pragma unroll
        for (int t = 0; t < NT; ++t) {
            unsigned long long msk = __ballot(mt == t);
            if (mt == t) mypos = run[t] + __popcll(msk & below);
            run[t] += __popcll(msk);
        }
        if (n < N) idx[mypos] = n;
    }
}

// ---------------------------------------------------------------------------
// K5: zero-LDS, zero-barrier register-dataflow GEMM.
//     Block = 64 rows, 4 waves, each wave owns a 16x128 output tile.
//     A fragments gathered per-lane straight from x (rows are lane-exclusive
//     in the 16x16x32 fragment layout); B fragments streamed from L2-resident
//     Wt (256 KB total); C stored directly from accumulators in 64B segments.
//     No __syncthreads, no LDS -> occupancy is VGPR-bound (16 waves/CU).
// ---------------------------------------------------------------------------
__global__ __launch_bounds__(256, 4) void k5_gemm(
    const float* __restrict__ x, const int* __restrict__ idx,
    const short* __restrict__ Wt, const float* __restrict__ Bias,
    const int* __restrict__ hist, float* __restrict__ out)
{
    int tid = threadIdx.x;
    int lane = tid & 63, w = tid >> 6;
    int m16 = lane & 15, quad = lane >> 4;
    int block_base = blockIdx.x * 64;

    int seg[NT + 1];
    {
        int s = 0;
        #pragma unroll
        for (int t = 0; t < NT; ++t) { seg[t] = s; s += ((hist[t] + 63) >> 6) << 6; }
        seg[NT] = s;
    }
    if (block_base >= seg[NT]) return;
    int t = 0;
    #pragma unroll
    for (int i = 1; i < NT; ++i)
        if (block_base >= seg[i]) t = i;

    int row0 = block_base + 16 * w;
    int node_a = idx[row0 + m16];

    // ---- A fragments: lane (quad,m16) owns row m16, k-slice quad*8 (+kk*32)
    short8 af[4];
    {
        const float* xr = x + (size_t)(node_a < 0 ? 0 : node_a) * C + quad * 8;
        #pragma unroll
        for (int kk = 0; kk < 4; ++kk) {
            float4 v0 = *(const float4*)(xr + kk * 32);
            float4 v1 = *(const float4*)(xr + kk * 32 + 4);
            short8 sv;
            sv[0] = f2bf(v0.x); sv[1] = f2bf(v0.y);
            sv[2] = f2bf(v0.z); sv[3] = f2bf(v0.w);
            sv[4] = f2bf(v1.x); sv[5] = f2bf(v1.y);
            sv[6] = f2bf(v1.z); sv[7] = f2bf(v1.w);
            af[kk] = sv;
        }
        if (node_a < 0) {
            #pragma unroll
            for (int kk = 0; kk < 4; ++kk)
                af[kk] = (short8){0, 0, 0, 0, 0, 0, 0, 0};
        }
    }

    f32x4 acc[8];
    #pragma unroll
    for (int i = 0; i < 8; ++i) acc[i] = (f32x4){0.f, 0.f, 0.f, 0.f};

    // ---- B fragments straight from L2-resident Wt[t][n][k]
    const short* bw = Wt + t * (C * C) + m16 * C + quad * 8;
    #pragma unroll
    for (int kk = 0; kk < 4; ++kk) {
        #pragma unroll
        for (int ni = 0; ni < 8; ++ni) {
            short8 bf = *(const short8*)(bw + (size_t)ni * 16 * C + kk * 32);
            acc[ni] = __builtin_amdgcn_mfma_f32_16x16x32_bf16(af[kk], bf, acc[ni], 0, 0, 0);
        }
    }

    // ---- epilogue: bias + direct stores (4 x 64B aligned segments / instr)
    int node_c[4];
    #pragma unroll
    for (int r = 0; r < 4; ++r) node_c[r] = idx[row0 + quad * 4 + r];

    #pragma unroll
    for (int ni = 0; ni < 8; ++ni) {
        float bv = Bias[t * C + ni * 16 + m16];
        #pragma unroll
        for (int r = 0; r < 4; ++r) {
            if (node_c[r] >= 0)
                out[(size_t)node_c[r] * C + ni * 16 + m16] = acc[ni][r] + bv;
        }
    }
}

// ---------------------------------------------------------------------------
extern "C" void kernel_launch(void* const* d_in, const int* in_sizes, int n_in,
                              void* d_out, int out_size, void* d_ws, size_t ws_size,
                              hipStream_t stream)
{
    const float* x         = (const float*)d_in[0];
    const int*   type_vec  = (const int*)d_in[1];
    const float* edge_feas = (const float*)d_in[2];
    const float* wg_w1 = (const float*)d_in[3];
    const float* wg_b1 = (const float*)d_in[4];
    const float* wg_w2 = (const float*)d_in[5];
    const float* wg_b2 = (const float*)d_in[6];
    const float* wg_w3 = (const float*)d_in[7];
    const float* wg_b3 = (const float*)d_in[8];
    const float* bg_w1 = (const float*)d_in[9];
    const float* bg_b1 = (const float*)d_in[10];
    const float* bg_w2 = (const float*)d_in[11];
    const float* bg_b2 = (const float*)d_in[12];
    const float* bg_w3 = (const float*)d_in[13];
    const float* bg_b3 = (const float*)d_in[14];
    float* out = (float*)d_out;
    int N = in_sizes[1];

    char* ws = (char*)d_ws;
    int*   hist   = (int*)(ws + 0);        // 8 ints
    int*   cursor = (int*)(ws + 128);      // 8 ints, 64B stride
    float* h_wg   = (float*)(ws + 1024);   // 8*256 f32
    float* h_bg   = (float*)(ws + 9216);   // 8*256 f32
    float* Bias   = (float*)(ws + 17408);  // 8*128 f32
    short* Wkn    = (short*)(ws + 21504);  // 8*128*128 bf16 [t][k][n]
    short* Wt     = (short*)(ws + 283648); // 8*128*128 bf16 [t][n][k]
    int*   idx    = (int*)(ws + 545792);   // (ceil(N/64)+8)*64 ints

    int nblk64  = (N + 63) / 64;
    int idx_cap = (nblk64 + 8) * 64;
    int n_init  = (idx_cap + 1023) / 1024;
    int n_hist  = (N + 1023) / 1024;
    int n_scat  = (n_hist + 3) / 4;

    k1_init_genh<<<n_init + 17, 256, 0, stream>>>(
        edge_feas, wg_w1, wg_b1, wg_w2, wg_b2, bg_w1, bg_b1, bg_w2, bg_b2,
        hist, cursor, idx, idx_cap, h_wg, h_bg, n_init);

    k2_hist_genw<<<n_hist + 257, 256, 0, stream>>>(
        type_vec, N, h_wg, h_bg, wg_w3, wg_b3, bg_w3, bg_b3,
        hist, Wkn, Bias, n_hist);

    k4_scatter_transpose<<<n_scat + 8, 256, 0, stream>>>(
        type_vec, N, hist, cursor, idx, Wkn, Wt, n_scat);

    k5_gemm<<<nblk64 + 8, 256, 0, stream>>>(x, idx, Wt, Bias, hist, out);
}

// Round 3
// 554.430 us; speedup vs baseline: 1.1100x; 1.1100x over previous
//
#include <hip/hip_runtime.h>
#include <hip/hip_bf16.h>

#define NT 8
#define MEMC 512
#define HID 256
#define C 128   // IN_C == OUT_C

typedef __attribute__((ext_vector_type(8))) short short8;
typedef __attribute__((ext_vector_type(4))) float f32x4;

__device__ inline short f2bf(float f) {
    union { __hip_bfloat16 b; short s; } u;
    u.b = __float2bfloat16(f);
    return u.s;
}

// ---------------------------------------------------------------------------
// K1: idx init (-1), hist+cursor zero, generator hidden layers h_wg/h_bg
//     [8][256].  Generator blocks: 4-way wave K-split + LDS reduce.
// ---------------------------------------------------------------------------
__global__ __launch_bounds__(256) void k1_init_genh(
    const float* __restrict__ edge_feas,
    const float* __restrict__ wg_w1, const float* __restrict__ wg_b1,
    const float* __restrict__ wg_w2, const float* __restrict__ wg_b2,
    const float* __restrict__ bg_w1, const float* __restrict__ bg_b1,
    const float* __restrict__ bg_w2, const float* __restrict__ bg_b2,
    int* __restrict__ hist, int* __restrict__ cursor,
    int* __restrict__ idx, int idx_cap,
    float* __restrict__ h_wg, float* __restrict__ h_bg,
    int n_init_blocks)
{
    int b = blockIdx.x, tid = threadIdx.x;
    if (b < n_init_blocks) {
        int pos = b * 1024 + tid * 4;
        if (pos < idx_cap) *(int4*)(idx + pos) = make_int4(-1, -1, -1, -1);
        return;
    }
    if (b == n_init_blocks) {
        if (tid < NT) { hist[tid] = 0; cursor[tid * 16] = 0; }
        return;
    }
    int gb = b - n_init_blocks - 1;          // 0..15
    int t = gb & 7;
    int gen = gb >> 3;
    const float* w1 = gen ? bg_w1 : wg_w1;
    const float* b1 = gen ? bg_b1 : wg_b1;
    const float* w2 = gen ? bg_w2 : wg_w2;
    const float* b2 = gen ? bg_b2 : wg_b2;
    float* hout = gen ? h_bg : h_wg;

    __shared__ float m[MEMC];
    __shared__ float part[4][HID];
    __shared__ float h1[HID];
    m[tid]       = edge_feas[t * MEMC + tid];
    m[tid + 256] = edge_feas[t * MEMC + tid + 256];
    __syncthreads();

    int w = tid >> 6, l = tid & 63;
    // layer 1: K=512, wave w owns k in [w*128, w*128+128)
    {
        float ax = 0.f, ay = 0.f, az = 0.f, aw = 0.f;
        const float* wp = w1 + (size_t)(w * 128) * HID + 4 * l;
        #pragma unroll 8
        for (int k = 0; k < 128; ++k) {
            float4 v = *(const float4*)(wp + (size_t)k * HID);
            float mk = m[w * 128 + k];
            ax += mk * v.x; ay += mk * v.y; az += mk * v.z; aw += mk * v.w;
        }
        *(float4*)&part[w][4 * l] = make_float4(ax, ay, az, aw);
    }
    __syncthreads();
    {
        float s = part[0][tid] + part[1][tid] + part[2][tid] + part[3][tid] + b1[tid];
        h1[tid] = fmaxf(s, 0.f);
    }
    __syncthreads();
    // layer 2: K=256, wave w owns k in [w*64, w*64+64)
    {
        float ax = 0.f, ay = 0.f, az = 0.f, aw = 0.f;
        const float* wp = w2 + (size_t)(w * 64) * HID + 4 * l;
        #pragma unroll 8
        for (int k = 0; k < 64; ++k) {
            float4 v = *(const float4*)(wp + (size_t)k * HID);
            float hk = h1[w * 64 + k];
            ax += hk * v.x; ay += hk * v.y; az += hk * v.z; aw += hk * v.w;
        }
        *(float4*)&part[w][4 * l] = make_float4(ax, ay, az, aw);
    }
    __syncthreads();
    {
        float s = part[0][tid] + part[1][tid] + part[2][tid] + part[3][tid] + b2[tid];
        hout[t * HID + tid] = fmaxf(s, 0.f);
    }
}

// ---------------------------------------------------------------------------
// K2: type histogram (ballot-based, no LDS atomics) + third layers.
//   W blocks (256): 64 cols each, 4-way K-split, 8 types per load,
//                   written DIRECTLY transposed into Wt[t][n][k].
//   Bias block (1): 128 cols, 2-way K-split, 8 types per load.
// ---------------------------------------------------------------------------
__global__ __launch_bounds__(256) void k2_hist_genw(
    const int* __restrict__ type_vec, int N,
    const float* __restrict__ h_wg, const float* __restrict__ h_bg,
    const float* __restrict__ wg_w3, const float* __restrict__ wg_b3,
    const float* __restrict__ bg_w3, const float* __restrict__ bg_b3,
    int* __restrict__ hist, short* __restrict__ Wt, float* __restrict__ Bias,
    int n_hist_blocks)
{
    int b = blockIdx.x, tid = threadIdx.x;
    __shared__ float sh[2048];
    __shared__ float sp[2048];
    if (b < n_hist_blocks) {
        int lane = tid & 63, wv = tid >> 6;
        int start = b * 1024 + wv * 256;
        int cnt[NT];
        #pragma unroll
        for (int t = 0; t < NT; ++t) cnt[t] = 0;
        #pragma unroll
        for (int c = 0; c < 4; ++c) {
            int n = start + c * 64 + lane;
            int mt = (n < N) ? type_vec[n] : NT;
            #pragma unroll
            for (int t = 0; t < NT; ++t)
                cnt[t] += __popcll(__ballot(mt == t));
        }
        if (lane < NT) atomicAdd(&hist[lane], cnt[lane]);
        return;
    }
    int gb = b - n_hist_blocks;
    if (gb < 256) {
        for (int i = tid; i < 2048; i += 256) sh[i] = h_wg[i];
        __syncthreads();
        int cl = tid & 63, p = tid >> 6;
        int col = gb * 64 + cl;
        float acc[NT];
        #pragma unroll
        for (int t = 0; t < NT; ++t) acc[t] = 0.f;
        const float* wp = wg_w3 + (size_t)(p * 64) * (C * C) + col;
        #pragma unroll 8
        for (int j = 0; j < 64; ++j) {
            float v = wp[(size_t)j * (C * C)];
            #pragma unroll
            for (int t = 0; t < NT; ++t) acc[t] += sh[t * 256 + p * 64 + j] * v;
        }
        #pragma unroll
        for (int t = 0; t < NT; ++t) sp[p * 512 + t * 64 + cl] = acc[t];
        __syncthreads();
        #pragma unroll
        for (int r = 0; r < 2; ++r) {
            int o = tid + 256 * r;               // 0..511
            int t = o >> 6, c2 = o & 63;
            float s = sp[t * 64 + c2] + sp[512 + t * 64 + c2]
                    + sp[1024 + t * 64 + c2] + sp[1536 + t * 64 + c2]
                    + wg_b3[gb * 64 + c2];
            int flat = gb * 64 + c2;             // = k*128 + n
            Wt[t * (C * C) + (flat & 127) * C + (flat >> 7)] = f2bf(s);
        }
        return;
    }
    // bias block
    for (int i = tid; i < 2048; i += 256) sh[i] = h_bg[i];
    __syncthreads();
    int cl = tid & 127, p = tid >> 7;
    float acc[NT];
    #pragma unroll
    for (int t = 0; t < NT; ++t) acc[t] = 0.f;
    const float* wp = bg_w3 + (size_t)(p * 128) * C + cl;
    #pragma unroll 8
    for (int j = 0; j < 128; ++j) {
        float v = wp[(size_t)j * C];
        #pragma unroll
        for (int t = 0; t < NT; ++t) acc[t] += sh[t * 256 + p * 128 + j] * v;
    }
    #pragma unroll
    for (int t = 0; t < NT; ++t) sp[p * 1024 + t * 128 + cl] = acc[t];
    __syncthreads();
    #pragma unroll
    for (int r = 0; r < 4; ++r) {
        int o = tid + 256 * r;                   // 0..1023
        int t = o >> 7, c2 = o & 127;
        Bias[t * C + c2] = sp[t * 128 + c2] + sp[1024 + t * 128 + c2] + bg_b3[c2];
    }
}

// ---------------------------------------------------------------------------
// K4: ballot scatter into type-sorted idx[] (seg 128-aligned, from hist)
// ---------------------------------------------------------------------------
__global__ __launch_bounds__(256) void k4_scatter(
    const int* __restrict__ type_vec, int N,
    const int* __restrict__ hist, int* __restrict__ cursor,
    int* __restrict__ idx)
{
    int b = blockIdx.x, tid = threadIdx.x;
    int seg[NT];
    {
        int s = 0;
        #pragma unroll
        for (int t = 0; t < NT; ++t) { seg[t] = s; s += ((hist[t] + 127) >> 7) << 7; }
    }
    int lane = tid & 63;
    int wave = b * 4 + (tid >> 6);
    int start = wave * 1024;
    if (start >= N) return;

    int cnt[NT];
    #pragma unroll
    for (int t = 0; t < NT; ++t) cnt[t] = 0;
    for (int c = 0; c < 16; ++c) {
        int n = start + c * 64 + lane;
        int mt = (n < N) ? type_vec[n] : NT;
        #pragma unroll
        for (int t = 0; t < NT; ++t)
            cnt[t] += __popcll(__ballot(mt == t));
    }
    int base = 0;
    if (lane < NT) base = atomicAdd(&cursor[lane * 16], cnt[lane]);
    int run[NT];
    #pragma unroll
    for (int t = 0; t < NT; ++t) run[t] = seg[t] + __shfl(base, t, 64);
    unsigned long long below = (1ULL << lane) - 1ULL;
    for (int c = 0; c < 16; ++c) {
        int n = start + c * 64 + lane;
        int mt = (n < N) ? type_vec[n] : NT;
        int mypos = 0;
        #pragma unroll
        for (int t = 0; t < NT; ++t) {
            unsigned long long msk = __ballot(mt == t);
            if (mt == t) mypos = run[t] + __popcll(msk & below);
            run[t] += __popcll(msk);
        }
        if (n < N) idx[mypos] = n;
    }
}

// ---------------------------------------------------------------------------
// K5: hybrid GEMM. Block = 512 threads (8 waves) x 128 rows.
//     B (32 KB) staged once per block: coalesced global short8 loads ->
//     XOR-swizzled ds_write_b128 (write-side swizzle == read-side swizzle,
//     LDS slots linear). MFMA loop reads B-frags via ds_read_b128 at 2-way
//     conflict (free). A gathered per-lane straight from x; C stored
//     directly from accumulators. One __syncthreads().
// ---------------------------------------------------------------------------
__global__ __launch_bounds__(512, 6) void k5_gemm(
    const float* __restrict__ x, const int* __restrict__ idx,
    const short* __restrict__ Wt, const float* __restrict__ Bias,
    const int* __restrict__ hist, float* __restrict__ out)
{
    __shared__ short Bs[C * C];          // 32 KB
    int tid = threadIdx.x;
    int lane = tid & 63, w = tid >> 6;   // w: 0..7
    int m16 = lane & 15, quad = lane >> 4;
    int block_base = blockIdx.x * 128;

    int seg[NT + 1];
    {
        int s = 0;
        #pragma unroll
        for (int t = 0; t < NT; ++t) { seg[t] = s; s += ((hist[t] + 127) >> 7) << 7; }
        seg[NT] = s;
    }
    if (block_base >= seg[NT]) return;
    int t = 0;
    #pragma unroll
    for (int i = 1; i < NT; ++i)
        if (block_base >= seg[i]) t = i;

    int row0 = block_base + 16 * w;
    int node_a = idx[row0 + m16];

    // ---- B global loads: thread tid owns 16B-slots {tid + i*512} ----
    short8 bstg[4];
    {
        const short* wsrc = Wt + t * (C * C);
        #pragma unroll
        for (int i = 0; i < 4; ++i)
            bstg[i] = *(const short8*)(wsrc + (size_t)(i * 512 + tid) * 8);
    }

    // ---- A loads (issued while B is in flight) ----
    float4 a0[4], a1[4];
    {
        const float* xr = x + (size_t)(node_a < 0 ? 0 : node_a) * C + quad * 8;
        #pragma unroll
        for (int kk = 0; kk < 4; ++kk) {
            a0[kk] = *(const float4*)(xr + kk * 32);
            a1[kk] = *(const float4*)(xr + kk * 32 + 4);
        }
    }

    // ---- B LDS writes, swizzled: slot s=(row,sl) -> row*256 + ((sl^row%16)<<4)
    {
        #pragma unroll
        for (int i = 0; i < 4; ++i) {
            int s = i * 512 + tid;
            int row = s >> 4, sl = s & 15;
            *(short8*)((char*)Bs + row * 256 + ((sl ^ (row & 15)) << 4)) = bstg[i];
        }
    }

    __syncthreads();   // B in LDS, A in regs (vmcnt drained by barrier)

    // ---- convert A to bf16 fragments ----
    short8 af[4];
    #pragma unroll
    for (int kk = 0; kk < 4; ++kk) {
        short8 sv;
        sv[0] = f2bf(a0[kk].x); sv[1] = f2bf(a0[kk].y);
        sv[2] = f2bf(a0[kk].z); sv[3] = f2bf(a0[kk].w);
        sv[4] = f2bf(a1[kk].x); sv[5] = f2bf(a1[kk].y);
        sv[6] = f2bf(a1[kk].z); sv[7] = f2bf(a1[kk].w);
        af[kk] = sv;
    }
    if (node_a < 0) {
        #pragma unroll
        for (int kk = 0; kk < 4; ++kk)
            af[kk] = (short8){0, 0, 0, 0, 0, 0, 0, 0};
    }

    f32x4 acc[8];
    #pragma unroll
    for (int i = 0; i < 8; ++i) acc[i] = (f32x4){0.f, 0.f, 0.f, 0.f};

    // ---- MFMA loop: B-frag logical (row = ni*16+m16, sl = kk*4+quad)
    //      -> physical byte = row*256 + (((kk*4+quad)^m16)<<4)
    {
        const char* bbase = (const char*)Bs + m16 * 256;
        #pragma unroll
        for (int kk = 0; kk < 4; ++kk) {
            int cswz = (((kk * 4 + quad) ^ m16) << 4);
            #pragma unroll
            for (int ni = 0; ni < 8; ++ni) {
                short8 bf = *(const short8*)(bbase + (ni << 12) + cswz);
                acc[ni] = __builtin_amdgcn_mfma_f32_16x16x32_bf16(af[kk], bf, acc[ni], 0, 0, 0);
            }
        }
    }

    // ---- epilogue: bias + direct stores (64B segments per 16-lane group) ----
    int node_c[4];
    #pragma unroll
    for (int r = 0; r < 4; ++r) node_c[r] = idx[row0 + quad * 4 + r];

    #pragma unroll
    for (int ni = 0; ni < 8; ++ni) {
        float bv = Bias[t * C + ni * 16 + m16];
        #pragma unroll
        for (int r = 0; r < 4; ++r) {
            if (node_c[r] >= 0)
                out[(size_t)node_c[r] * C + ni * 16 + m16] = acc[ni][r] + bv;
        }
    }
}

// ---------------------------------------------------------------------------
extern "C" void kernel_launch(void* const* d_in, const int* in_sizes, int n_in,
                              void* d_out, int out_size, void* d_ws, size_t ws_size,
                              hipStream_t stream)
{
    const float* x         = (const float*)d_in[0];
    const int*   type_vec  = (const int*)d_in[1];
    const float* edge_feas = (const float*)d_in[2];
    const float* wg_w1 = (const float*)d_in[3];
    const float* wg_b1 = (const float*)d_in[4];
    const float* wg_w2 = (const float*)d_in[5];
    const float* wg_b2 = (const float*)d_in[6];
    const float* wg_w3 = (const float*)d_in[7];
    const float* wg_b3 = (const float*)d_in[8];
    const float* bg_w1 = (const float*)d_in[9];
    const float* bg_b1 = (const float*)d_in[10];
    const float* bg_w2 = (const float*)d_in[11];
    const float* bg_b2 = (const float*)d_in[12];
    const float* bg_w3 = (const float*)d_in[13];
    const float* bg_b3 = (const float*)d_in[14];
    float* out = (float*)d_out;
    int N = in_sizes[1];

    char* ws = (char*)d_ws;
    int*   hist   = (int*)(ws + 0);        // 8 ints
    int*   cursor = (int*)(ws + 128);      // 8 ints, 64B stride
    float* h_wg   = (float*)(ws + 1024);   // 8*256 f32
    float* h_bg   = (float*)(ws + 9216);   // 8*256 f32
    float* Bias   = (float*)(ws + 17408);  // 8*128 f32
    short* Wt     = (short*)(ws + 21504);  // 8*128*128 bf16 [t][n][k] (ends 283648)
    int*   idx    = (int*)(ws + 283648);   // (nblk128+8)*128 ints

    int nblk128 = (N + 127) / 128;
    int idx_cap = (nblk128 + 8) * 128;
    int n_init  = (idx_cap + 1023) / 1024;
    int n_hist  = (N + 1023) / 1024;
    int n_scat  = (n_hist + 3) / 4;

    k1_init_genh<<<n_init + 17, 256, 0, stream>>>(
        edge_feas, wg_w1, wg_b1, wg_w2, wg_b2, bg_w1, bg_b1, bg_w2, bg_b2,
        hist, cursor, idx, idx_cap, h_wg, h_bg, n_init);

    k2_hist_genw<<<n_hist + 257, 256, 0, stream>>>(
        type_vec, N, h_wg, h_bg, wg_w3, wg_b3, bg_w3, bg_b3,
        hist, Wt, Bias, n_hist);

    k4_scatter<<<n_scat, 256, 0, stream>>>(
        type_vec, N, hist, cursor, idx);

    k5_gemm<<<nblk128 + 8, 512, 0, stream>>>(x, idx, Wt, Bias, hist, out);
}

// Round 4
// 538.173 us; speedup vs baseline: 1.1436x; 1.0302x over previous
//
#include <hip/hip_runtime.h>
#include <hip/hip_bf16.h>

#define NT 8
#define MEMC 512
#define HID 256
#define C 128   // IN_C == OUT_C

typedef __attribute__((ext_vector_type(8))) short short8;
typedef __attribute__((ext_vector_type(4))) float f32x4;

__device__ inline short f2bf(float f) {
    union { __hip_bfloat16 b; short s; } u;
    u.b = __float2bfloat16(f);
    return u.s;
}

// ---------------------------------------------------------------------------
// K1: hist+cursor zero (block 0) + generator hidden layers h_wg/h_bg [8][256]
//     (blocks 1..16).  No idx init: k5 masks pad rows via hist counts.
// ---------------------------------------------------------------------------
__global__ __launch_bounds__(256) void k1_init_genh(
    const float* __restrict__ edge_feas,
    const float* __restrict__ wg_w1, const float* __restrict__ wg_b1,
    const float* __restrict__ wg_w2, const float* __restrict__ wg_b2,
    const float* __restrict__ bg_w1, const float* __restrict__ bg_b1,
    const float* __restrict__ bg_w2, const float* __restrict__ bg_b2,
    int* __restrict__ hist, int* __restrict__ cursor,
    float* __restrict__ h_wg, float* __restrict__ h_bg)
{
    int b = blockIdx.x, tid = threadIdx.x;
    if (b == 0) {
        if (tid < NT) { hist[tid] = 0; cursor[tid * 16] = 0; }
        return;
    }
    int gb = b - 1;                          // 0..15
    int t = gb & 7;
    int gen = gb >> 3;
    const float* w1 = gen ? bg_w1 : wg_w1;
    const float* b1 = gen ? bg_b1 : wg_b1;
    const float* w2 = gen ? bg_w2 : wg_w2;
    const float* b2 = gen ? bg_b2 : wg_b2;
    float* hout = gen ? h_bg : h_wg;

    __shared__ float m[MEMC];
    __shared__ float part[4][HID];
    __shared__ float h1[HID];
    m[tid]       = edge_feas[t * MEMC + tid];
    m[tid + 256] = edge_feas[t * MEMC + tid + 256];
    __syncthreads();

    int w = tid >> 6, l = tid & 63;
    // layer 1: K=512, wave w owns k in [w*128, w*128+128)
    {
        float ax = 0.f, ay = 0.f, az = 0.f, aw = 0.f;
        const float* wp = w1 + (size_t)(w * 128) * HID + 4 * l;
        #pragma unroll 8
        for (int k = 0; k < 128; ++k) {
            float4 v = *(const float4*)(wp + (size_t)k * HID);
            float mk = m[w * 128 + k];
            ax += mk * v.x; ay += mk * v.y; az += mk * v.z; aw += mk * v.w;
        }
        *(float4*)&part[w][4 * l] = make_float4(ax, ay, az, aw);
    }
    __syncthreads();
    {
        float s = part[0][tid] + part[1][tid] + part[2][tid] + part[3][tid] + b1[tid];
        h1[tid] = fmaxf(s, 0.f);
    }
    __syncthreads();
    // layer 2: K=256, wave w owns k in [w*64, w*64+64)
    {
        float ax = 0.f, ay = 0.f, az = 0.f, aw = 0.f;
        const float* wp = w2 + (size_t)(w * 64) * HID + 4 * l;
        #pragma unroll 8
        for (int k = 0; k < 64; ++k) {
            float4 v = *(const float4*)(wp + (size_t)k * HID);
            float hk = h1[w * 64 + k];
            ax += hk * v.x; ay += hk * v.y; az += hk * v.z; aw += hk * v.w;
        }
        *(float4*)&part[w][4 * l] = make_float4(ax, ay, az, aw);
    }
    __syncthreads();
    {
        float s = part[0][tid] + part[1][tid] + part[2][tid] + part[3][tid] + b2[tid];
        hout[t * HID + tid] = fmaxf(s, 0.f);
    }
}

// ---------------------------------------------------------------------------
// K2: type histogram (ballot-based) + third layers.
//   W blocks (256): 64 cols each, 4-way K-split, 8 types per load,
//                   written DIRECTLY transposed into Wt[t][n][k].
//   Bias block (1): 128 cols, 2-way K-split, 8 types per load.
// ---------------------------------------------------------------------------
__global__ __launch_bounds__(256) void k2_hist_genw(
    const int* __restrict__ type_vec, int N,
    const float* __restrict__ h_wg, const float* __restrict__ h_bg,
    const float* __restrict__ wg_w3, const float* __restrict__ wg_b3,
    const float* __restrict__ bg_w3, const float* __restrict__ bg_b3,
    int* __restrict__ hist, short* __restrict__ Wt, float* __restrict__ Bias,
    int n_hist_blocks)
{
    int b = blockIdx.x, tid = threadIdx.x;
    __shared__ float sh[2048];
    __shared__ float sp[2048];
    if (b < n_hist_blocks) {
        int lane = tid & 63, wv = tid >> 6;
        int start = b * 1024 + wv * 256;
        int cnt[NT];
        #pragma unroll
        for (int t = 0; t < NT; ++t) cnt[t] = 0;
        #pragma unroll
        for (int c = 0; c < 4; ++c) {
            int n = start + c * 64 + lane;
            int mt = (n < N) ? type_vec[n] : NT;
            #pragma unroll
            for (int t = 0; t < NT; ++t)
                cnt[t] += __popcll(__ballot(mt == t));
        }
        if (lane < NT) atomicAdd(&hist[lane], cnt[lane]);
        return;
    }
    int gb = b - n_hist_blocks;
    if (gb < 256) {
        for (int i = tid; i < 2048; i += 256) sh[i] = h_wg[i];
        __syncthreads();
        int cl = tid & 63, p = tid >> 6;
        int col = gb * 64 + cl;
        float acc[NT];
        #pragma unroll
        for (int t = 0; t < NT; ++t) acc[t] = 0.f;
        const float* wp = wg_w3 + (size_t)(p * 64) * (C * C) + col;
        #pragma unroll 8
        for (int j = 0; j < 64; ++j) {
            float v = wp[(size_t)j * (C * C)];
            #pragma unroll
            for (int t = 0; t < NT; ++t) acc[t] += sh[t * 256 + p * 64 + j] * v;
        }
        #pragma unroll
        for (int t = 0; t < NT; ++t) sp[p * 512 + t * 64 + cl] = acc[t];
        __syncthreads();
        #pragma unroll
        for (int r = 0; r < 2; ++r) {
            int o = tid + 256 * r;               // 0..511
            int t = o >> 6, c2 = o & 63;
            float s = sp[t * 64 + c2] + sp[512 + t * 64 + c2]
                    + sp[1024 + t * 64 + c2] + sp[1536 + t * 64 + c2]
                    + wg_b3[gb * 64 + c2];
            int flat = gb * 64 + c2;             // = k*128 + n
            Wt[t * (C * C) + (flat & 127) * C + (flat >> 7)] = f2bf(s);
        }
        return;
    }
    // bias block
    for (int i = tid; i < 2048; i += 256) sh[i] = h_bg[i];
    __syncthreads();
    int cl = tid & 127, p = tid >> 7;
    float acc[NT];
    #pragma unroll
    for (int t = 0; t < NT; ++t) acc[t] = 0.f;
    const float* wp = bg_w3 + (size_t)(p * 128) * C + cl;
    #pragma unroll 8
    for (int j = 0; j < 128; ++j) {
        float v = wp[(size_t)j * C];
        #pragma unroll
        for (int t = 0; t < NT; ++t) acc[t] += sh[t * 256 + p * 128 + j] * v;
    }
    #pragma unroll
    for (int t = 0; t < NT; ++t) sp[p * 1024 + t * 128 + cl] = acc[t];
    __syncthreads();
    #pragma unroll
    for (int r = 0; r < 4; ++r) {
        int o = tid + 256 * r;                   // 0..1023
        int t = o >> 7, c2 = o & 127;
        Bias[t * C + c2] = sp[t * 128 + c2] + sp[1024 + t * 128 + c2] + bg_b3[c2];
    }
}

// ---------------------------------------------------------------------------
// K4: ballot scatter into type-sorted idx[] (seg 128-aligned, from hist).
//     256 elems/wave (4x parallelism vs prior), block-aggregated cursor
//     atomics (same atomic count per counter as before).
// ---------------------------------------------------------------------------
__global__ __launch_bounds__(256) void k4_scatter(
    const int* __restrict__ type_vec, int N,
    const int* __restrict__ hist, int* __restrict__ cursor,
    int* __restrict__ idx)
{
    int b = blockIdx.x, tid = threadIdx.x;
    int lane = tid & 63, wv = tid >> 6;
    __shared__ int pb[4][NT];

    int seg[NT];
    {
        int s = 0;
        #pragma unroll
        for (int t = 0; t < NT; ++t) { seg[t] = s; s += ((hist[t] + 127) >> 7) << 7; }
    }
    int start = b * 1024 + wv * 256;

    // pass 1: per-wave counts
    int cnt[NT];
    #pragma unroll
    for (int t = 0; t < NT; ++t) cnt[t] = 0;
    #pragma unroll
    for (int c = 0; c < 4; ++c) {
        int n = start + c * 64 + lane;
        int mt = (n < N) ? type_vec[n] : NT;
        #pragma unroll
        for (int t = 0; t < NT; ++t)
            cnt[t] += __popcll(__ballot(mt == t));
    }
    if (lane < NT) pb[wv][lane] = cnt[lane];
    __syncthreads();
    // block aggregate: one atomic per type, per-wave prefix redistribution
    if (tid < NT) {
        int s0 = pb[0][tid], s1 = pb[1][tid], s2 = pb[2][tid], s3 = pb[3][tid];
        int base = atomicAdd(&cursor[tid * 16], s0 + s1 + s2 + s3);
        pb[0][tid] = base;
        pb[1][tid] = base + s0;
        pb[2][tid] = base + s0 + s1;
        pb[3][tid] = base + s0 + s1 + s2;
    }
    __syncthreads();
    int run[NT];
    #pragma unroll
    for (int t = 0; t < NT; ++t) run[t] = seg[t] + pb[wv][t];

    // pass 2: rank within wave chunk, scatter
    unsigned long long below = (1ULL << lane) - 1ULL;
    #pragma unroll
    for (int c = 0; c < 4; ++c) {
        int n = start + c * 64 + lane;
        int mt = (n < N) ? type_vec[n] : NT;
        int mypos = 0;
        #pragma unroll
        for (int t = 0; t < NT; ++t) {
            unsigned long long msk = __ballot(mt == t);
            if (mt == t) mypos = run[t] + __popcll(msk & below);
            run[t] += __popcll(msk);
        }
        if (n < N) idx[mypos] = n;
    }
}

// ---------------------------------------------------------------------------
// K5: hybrid GEMM. Block = 512 threads (8 waves) x 128 rows.
//     B (32 KB) staged once per block: coalesced global short8 loads ->
//     XOR-swizzled ds_write_b128; MFMA loop reads B-frags via ds_read_b128.
//     A gathered per-lane straight from x; C stored directly from acc.
//     Row validity from hist (pad idx entries never dereferenced).
//     launch_bounds(512,4): VGPR<=128 (no spill at ~115 peak live),
//     16 waves/CU, 2 blocks/CU (LDS 64 KB).
// ---------------------------------------------------------------------------
__global__ __launch_bounds__(512, 4) void k5_gemm(
    const float* __restrict__ x, const int* __restrict__ idx,
    const short* __restrict__ Wt, const float* __restrict__ Bias,
    const int* __restrict__ hist, float* __restrict__ out)
{
    __shared__ short Bs[C * C];          // 32 KB
    int tid = threadIdx.x;
    int lane = tid & 63, w = tid >> 6;   // w: 0..7
    int m16 = lane & 15, quad = lane >> 4;
    int block_base = blockIdx.x * 128;

    int seg[NT + 1], harr[NT];
    {
        int s = 0;
        #pragma unroll
        for (int t = 0; t < NT; ++t) {
            harr[t] = hist[t];
            seg[t] = s;
            s += ((harr[t] + 127) >> 7) << 7;
        }
        seg[NT] = s;
    }
    if (block_base >= seg[NT]) return;
    int t = 0;
    #pragma unroll
    for (int i = 1; i < NT; ++i)
        if (block_base >= seg[i]) t = i;
    int vlim = 0;                         // first invalid row in this segment
    #pragma unroll
    for (int i = 0; i < NT; ++i)
        if (i == t) vlim = seg[i] + harr[i];

    int row0 = block_base + 16 * w;
    int rowA = row0 + m16;
    bool validA = rowA < vlim;
    int node_a = idx[rowA];               // allocated; gated before use
    int na = validA ? node_a : 0;

    // ---- B global loads: thread tid owns 16B-slots {tid + i*512} ----
    short8 bstg[4];
    {
        const short* wsrc = Wt + t * (C * C);
        #pragma unroll
        for (int i = 0; i < 4; ++i)
            bstg[i] = *(const short8*)(wsrc + (size_t)(i * 512 + tid) * 8);
    }

    // ---- A loads (in flight alongside B) ----
    float4 a0[4], a1[4];
    {
        const float* xr = x + (size_t)na * C + quad * 8;
        #pragma unroll
        for (int kk = 0; kk < 4; ++kk) {
            a0[kk] = *(const float4*)(xr + kk * 32);
            a1[kk] = *(const float4*)(xr + kk * 32 + 4);
        }
    }

    // ---- epilogue operands hoisted: C-row nodes + bias ----
    int node_c[4];
    bool valid_c[4];
    #pragma unroll
    for (int r = 0; r < 4; ++r) {
        int rowC = row0 + quad * 4 + r;
        valid_c[r] = rowC < vlim;
        node_c[r] = idx[rowC];
    }
    float bv[8];
    #pragma unroll
    for (int ni = 0; ni < 8; ++ni) bv[ni] = Bias[t * C + ni * 16 + m16];

    // ---- B LDS writes, swizzled: slot s=(row,sl) -> row*256 + ((sl^row%16)<<4)
    {
        #pragma unroll
        for (int i = 0; i < 4; ++i) {
            int s = i * 512 + tid;
            int row = s >> 4, sl = s & 15;
            *(short8*)((char*)Bs + row * 256 + ((sl ^ (row & 15)) << 4)) = bstg[i];
        }
    }

    __syncthreads();   // B in LDS, A in regs

    // ---- convert A to bf16 fragments ----
    short8 af[4];
    #pragma unroll
    for (int kk = 0; kk < 4; ++kk) {
        short8 sv;
        sv[0] = f2bf(a0[kk].x); sv[1] = f2bf(a0[kk].y);
        sv[2] = f2bf(a0[kk].z); sv[3] = f2bf(a0[kk].w);
        sv[4] = f2bf(a1[kk].x); sv[5] = f2bf(a1[kk].y);
        sv[6] = f2bf(a1[kk].z); sv[7] = f2bf(a1[kk].w);
        af[kk] = sv;
    }
    if (!validA) {
        #pragma unroll
        for (int kk = 0; kk < 4; ++kk)
            af[kk] = (short8){0, 0, 0, 0, 0, 0, 0, 0};
    }

    f32x4 acc[8];
    #pragma unroll
    for (int i = 0; i < 8; ++i) acc[i] = (f32x4){0.f, 0.f, 0.f, 0.f};

    // ---- MFMA loop: B-frag logical (row = ni*16+m16, sl = kk*4+quad)
    //      -> physical byte = row*256 + (((kk*4+quad)^m16)<<4)
    {
        const char* bbase = (const char*)Bs + m16 * 256;
        #pragma unroll
        for (int kk = 0; kk < 4; ++kk) {
            int cswz = (((kk * 4 + quad) ^ m16) << 4);
            #pragma unroll
            for (int ni = 0; ni < 8; ++ni) {
                short8 bf = *(const short8*)(bbase + (ni << 12) + cswz);
                acc[ni] = __builtin_amdgcn_mfma_f32_16x16x32_bf16(af[kk], bf, acc[ni], 0, 0, 0);
            }
        }
    }

    // ---- stores: 16-lane groups write 64B contiguous per (ni, r) ----
    #pragma unroll
    for (int ni = 0; ni < 8; ++ni) {
        #pragma unroll
        for (int r = 0; r < 4; ++r) {
            if (valid_c[r])
                out[(size_t)node_c[r] * C + ni * 16 + m16] = acc[ni][r] + bv[ni];
        }
    }
}

// ---------------------------------------------------------------------------
extern "C" void kernel_launch(void* const* d_in, const int* in_sizes, int n_in,
                              void* d_out, int out_size, void* d_ws, size_t ws_size,
                              hipStream_t stream)
{
    const float* x         = (const float*)d_in[0];
    const int*   type_vec  = (const int*)d_in[1];
    const float* edge_feas = (const float*)d_in[2];
    const float* wg_w1 = (const float*)d_in[3];
    const float* wg_b1 = (const float*)d_in[4];
    const float* wg_w2 = (const float*)d_in[5];
    const float* wg_b2 = (const float*)d_in[6];
    const float* wg_w3 = (const float*)d_in[7];
    const float* wg_b3 = (const float*)d_in[8];
    const float* bg_w1 = (const float*)d_in[9];
    const float* bg_b1 = (const float*)d_in[10];
    const float* bg_w2 = (const float*)d_in[11];
    const float* bg_b2 = (const float*)d_in[12];
    const float* bg_w3 = (const float*)d_in[13];
    const float* bg_b3 = (const float*)d_in[14];
    float* out = (float*)d_out;
    int N = in_sizes[1];

    char* ws = (char*)d_ws;
    int*   hist   = (int*)(ws + 0);        // 8 ints
    int*   cursor = (int*)(ws + 128);      // 8 ints, 64B stride
    float* h_wg   = (float*)(ws + 1024);   // 8*256 f32
    float* h_bg   = (float*)(ws + 9216);   // 8*256 f32
    float* Bias   = (float*)(ws + 17408);  // 8*128 f32
    short* Wt     = (short*)(ws + 21504);  // 8*128*128 bf16 [t][n][k] (ends 283648)
    int*   idx    = (int*)(ws + 283648);   // (nblk128+8)*128 ints, NOT pre-initialized

    int nblk128 = (N + 127) / 128;
    int n_hist  = (N + 1023) / 1024;

    k1_init_genh<<<17, 256, 0, stream>>>(
        edge_feas, wg_w1, wg_b1, wg_w2, wg_b2, bg_w1, bg_b1, bg_w2, bg_b2,
        hist, cursor, h_wg, h_bg);

    k2_hist_genw<<<n_hist + 257, 256, 0, stream>>>(
        type_vec, N, h_wg, h_bg, wg_w3, wg_b3, bg_w3, bg_b3,
        hist, Wt, Bias, n_hist);

    k4_scatter<<<n_hist, 256, 0, stream>>>(
        type_vec, N, hist, cursor, idx);

    k5_gemm<<<nblk128 + 8, 512, 0, stream>>>(x, idx, Wt, Bias, hist, out);
}